// Round 2
// baseline (113.077 us; speedup 1.0000x reference)
//
#include <hip/hip_runtime.h>
#include <hip/hip_bf16.h>
#include <math.h>

typedef __bf16 bf16_t;
typedef __bf16 bf16x8 __attribute__((ext_vector_type(8)));
typedef float f32x4 __attribute__((ext_vector_type(4)));

#define N2 4096
#define NHALF 2048
#define DIM 512
#define TEMP_INV 2.0f   // 1/TEMPERATURE
#define NBLK 528        // upper-triangle 32x32 of 128-tiles

// ---------------------------------------------------------------------------
// Kernel 1 (fused prep): one wave per row-PAIR (i, i+N). Loads both fp32 rows,
// computes norms + cross-dot, writes both bf16 rows, pos[i]=pos[p] (symmetric),
// diag per row from the bf16-rounded values (matches what the GEMM will sum),
// zeroes this block's slice of rowsum, and block 0 zeroes the done-counter.
// ---------------------------------------------------------------------------
__global__ __launch_bounds__(256) void k_prep(const float* __restrict__ x,
                                              bf16_t* __restrict__ xn,
                                              float* __restrict__ pos,
                                              float* __restrict__ diag,
                                              float* __restrict__ rowsum,
                                              int* __restrict__ counter) {
    const int pair = blockIdx.x * 4 + (threadIdx.x >> 6);   // 0..2047
    const int lane = threadIdx.x & 63;
    const int rowi = pair;
    const int rowp = pair + NHALF;

    const float4* xi = reinterpret_cast<const float4*>(x + (size_t)rowi * DIM);
    const float4* xp = reinterpret_cast<const float4*>(x + (size_t)rowp * DIM);
    float4 a0 = xi[lane * 2], a1 = xi[lane * 2 + 1];
    float4 b0 = xp[lane * 2], b1 = xp[lane * 2 + 1];

    float ssi = a0.x*a0.x + a0.y*a0.y + a0.z*a0.z + a0.w*a0.w
              + a1.x*a1.x + a1.y*a1.y + a1.z*a1.z + a1.w*a1.w;
    float ssp = b0.x*b0.x + b0.y*b0.y + b0.z*b0.z + b0.w*b0.w
              + b1.x*b1.x + b1.y*b1.y + b1.z*b1.z + b1.w*b1.w;
    float dot = a0.x*b0.x + a0.y*b0.y + a0.z*b0.z + a0.w*b0.w
              + a1.x*b1.x + a1.y*b1.y + a1.z*b1.z + a1.w*b1.w;
#pragma unroll
    for (int off = 32; off; off >>= 1) {
        ssi += __shfl_xor(ssi, off, 64);
        ssp += __shfl_xor(ssp, off, 64);
        dot += __shfl_xor(dot, off, 64);
    }
    const float ni = fmaxf(sqrtf(ssi), 1e-8f);
    const float np = fmaxf(sqrtf(ssp), 1e-8f);
    const float sci = 1.0f / ni, scp = 1.0f / np;

    float va[8] = {a0.x, a0.y, a0.z, a0.w, a1.x, a1.y, a1.z, a1.w};
    float vb[8] = {b0.x, b0.y, b0.z, b0.w, b1.x, b1.y, b1.z, b1.w};
    bf16x8 oi, op;
    float dii = 0.0f, dpp = 0.0f;
#pragma unroll
    for (int t = 0; t < 8; ++t) {
        oi[t] = (bf16_t)(va[t] * sci);
        op[t] = (bf16_t)(vb[t] * scp);
        float fi = (float)oi[t], fp_ = (float)op[t];
        dii += fi * fi;
        dpp += fp_ * fp_;
    }
    *reinterpret_cast<bf16x8*>(xn + (size_t)rowi * DIM + lane * 8) = oi;
    *reinterpret_cast<bf16x8*>(xn + (size_t)rowp * DIM + lane * 8) = op;
#pragma unroll
    for (int off = 32; off; off >>= 1) {
        dii += __shfl_xor(dii, off, 64);
        dpp += __shfl_xor(dpp, off, 64);
    }
    if (lane == 0) {
        const float pv = TEMP_INV * dot * sci * scp;
        pos[rowi] = pv;
        pos[rowp] = pv;          // sim is symmetric: pos[i] == pos[i+N]
        diag[rowi] = TEMP_INV * dii;
        diag[rowp] = TEMP_INV * dpp;
    }
    // zero rowsum (8 entries per block covers 4096 over 512 blocks)
    if (threadIdx.x < 8) rowsum[blockIdx.x * 8 + threadIdx.x] = 0.0f;
    if (blockIdx.x == 0 && threadIdx.x == 8) *counter = 0;
}

// ---------------------------------------------------------------------------
// Kernel 2: symmetric sim-GEMM, upper-triangle blocks only (528 of 1024).
// 128x128 tile, 4 waves 2x2, BK=32 double-buffered (LDS 33KB -> 4 blocks/CU
// by LDS, so all 528 blocks co-schedule: round-0's co-residency + round-1's
// 1-deep prefetch). Single __syncthreads per K-step: its vmcnt(0)+lgkmcnt(0)
// drain lands AFTER ds_read+MFMA covered the prefetch latency.
// Finalize is fused via last-block-done (device-scope counter).
// ---------------------------------------------------------------------------
__device__ __forceinline__ void load_lds16(const bf16_t* g, bf16_t* l) {
    __builtin_amdgcn_global_load_lds(
        (const __attribute__((address_space(1))) unsigned int*)g,
        (__attribute__((address_space(3))) unsigned int*)l,
        16, 0, 0);
}

__global__ __launch_bounds__(256) void k_simgemm(const bf16_t* __restrict__ xn,
                                                 float* __restrict__ rowsum,
                                                 const float* __restrict__ pos,
                                                 const float* __restrict__ diag,
                                                 int* __restrict__ counter,
                                                 float* __restrict__ out) {
    __shared__ bf16_t As[2][128 * 32];   // 2 x 8KB
    __shared__ bf16_t Bs[2][128 * 32];   // 2 x 8KB
    __shared__ float  rpA[128];
    __shared__ float  rpB[128];
    __shared__ int    lastBlk;

    // unrank blockIdx.x -> (bm <= bn) upper-triangle pair
    const int t = blockIdx.x;
    int bn = (int)((sqrtf(8.0f * (float)t + 1.0f) - 1.0f) * 0.5f);
    while ((bn * (bn + 1)) / 2 > t) --bn;
    while (((bn + 1) * (bn + 2)) / 2 <= t) ++bn;
    const int bm = t - (bn * (bn + 1)) / 2;
    const bool diagb = (bm == bn);

    const int tid  = threadIdx.x;
    const int lane = tid & 63;
    const int wid  = tid >> 6;
    const int wr   = wid >> 1;
    const int wc   = wid & 1;
    const int q    = lane >> 4;
    const int l15  = lane & 15;

    if (tid < 128) { rpA[tid] = 0.0f; rpB[tid] = 0.0f; }

    // Staging: one K-tile = 128 rows x 32 cols bf16 = 8KB = 256 thr x 2x16B.
    // thread t covers rows (t>>2) and 64+(t>>2), col (t&3)*8.
    // LDS linear: (row)*32 + col == t*8 (+ 2048 for second half). Wave-uniform
    // base + lane*16B as required by global_load_lds.
    const bf16_t* gA = xn + (size_t)(bm * 128 + (tid >> 2)) * DIM + (tid & 3) * 8;
    const bf16_t* gB = xn + (size_t)(bn * 128 + (tid >> 2)) * DIM + (tid & 3) * 8;

    f32x4 acc[4][4] = {};

    // prologue: stage K-tile 0 into buffer 0
    load_lds16(gA,                       &As[0][tid * 8]);
    load_lds16(gA + (size_t)64 * DIM,    &As[0][2048 + tid * 8]);
    load_lds16(gB,                       &Bs[0][tid * 8]);
    load_lds16(gB + (size_t)64 * DIM,    &Bs[0][2048 + tid * 8]);
    __syncthreads();   // vmcnt(0) drain: tile 0 resident

    for (int kt = 0; kt < 16; ++kt) {
        const int cur = kt & 1;
        // phase A: issue next K-tile's loads into the other buffer.
        // Safe: buf cur^1 was last ds_read at iter kt-1, whose ending
        // __syncthreads (lgkmcnt(0)) guarantees those reads retired.
        if (kt < 15) {
            const bf16_t* gA1 = gA + (size_t)(kt + 1) * 32;
            const bf16_t* gB1 = gB + (size_t)(kt + 1) * 32;
            load_lds16(gA1,                    &As[cur ^ 1][tid * 8]);
            load_lds16(gA1 + (size_t)64 * DIM, &As[cur ^ 1][2048 + tid * 8]);
            load_lds16(gB1,                    &Bs[cur ^ 1][tid * 8]);
            load_lds16(gB1 + (size_t)64 * DIM, &Bs[cur ^ 1][2048 + tid * 8]);
        }
        // phase B: compute current tile
        bf16x8 af[4], bv[4];
#pragma unroll
        for (int mt = 0; mt < 4; ++mt)
            af[mt] = *reinterpret_cast<const bf16x8*>(
                &As[cur][(wr * 64 + mt * 16 + l15) * 32 + q * 8]);
#pragma unroll
        for (int nt = 0; nt < 4; ++nt)
            bv[nt] = *reinterpret_cast<const bf16x8*>(
                &Bs[cur][(wc * 64 + nt * 16 + l15) * 32 + q * 8]);
#pragma unroll
        for (int mt = 0; mt < 4; ++mt)
#pragma unroll
            for (int nt = 0; nt < 4; ++nt)
                acc[mt][nt] = __builtin_amdgcn_mfma_f32_16x16x32_bf16(
                    af[mt], bv[nt], acc[mt][nt], 0, 0, 0);
        // single barrier per K-step: drains vmcnt(0) (next tile staged) and
        // lgkmcnt(0) (this tile's ds_reads retired) AFTER compute covered them
        __syncthreads();
    }

    // Epilogue. C/D: row = wr*64+mt*16+q*4+r, col = wc*64+nt*16+l15.
    float colacc[4] = {0.0f, 0.0f, 0.0f, 0.0f};
#pragma unroll
    for (int mt = 0; mt < 4; ++mt) {
        float rowp[4] = {0.0f, 0.0f, 0.0f, 0.0f};
#pragma unroll
        for (int nt = 0; nt < 4; ++nt)
#pragma unroll
            for (int r = 0; r < 4; ++r) {
                float e = __expf(TEMP_INV * acc[mt][nt][r]);
                rowp[r] += e;
                colacc[nt] += e;
            }
#pragma unroll
        for (int r = 0; r < 4; ++r) {
            float p = rowp[r];
            p += __shfl_xor(p, 1, 64);
            p += __shfl_xor(p, 2, 64);
            p += __shfl_xor(p, 4, 64);
            p += __shfl_xor(p, 8, 64);
            if (l15 == 0) atomicAdd(&rpA[wr * 64 + mt * 16 + q * 4 + r], p);
        }
    }
    if (!diagb) {
#pragma unroll
        for (int nt = 0; nt < 4; ++nt) {
            float c = colacc[nt];
            c += __shfl_xor(c, 16, 64);
            c += __shfl_xor(c, 32, 64);
            if (q == 0) atomicAdd(&rpB[wc * 64 + nt * 16 + l15], c);
        }
    }
    __syncthreads();
    if (tid < 128) {
        atomicAdd(&rowsum[bm * 128 + tid], rpA[tid]);
    } else if (!diagb) {
        atomicAdd(&rowsum[bn * 128 + (tid - 128)], rpB[tid - 128]);
    }

    // ---- fused finalize: last block computes the loss ----
    __threadfence();                       // make rowsum atomics visible
    if (tid == 0) {
        int prev = atomicAdd(counter, 1);
        lastBlk = (prev == NBLK - 1);
    }
    __syncthreads();
    if (!lastBlk) return;

    __threadfence();
    float* red = reinterpret_cast<float*>(As);   // reuse LDS
    float s = 0.0f;
#pragma unroll
    for (int it = 0; it < 16; ++it) {
        const int i = it * 256 + tid;
        // atomicAdd(p, 0) reads through the coherent point (other XCDs' L2
        // writes must be visible); pos/diag came from the previous kernel.
        float r = atomicAdd(&rowsum[i], 0.0f);
        s += __logf(r - __expf(diag[i])) - pos[i];
    }
    red[tid] = s;
    __syncthreads();
    for (int st = 128; st; st >>= 1) {
        if (tid < st) red[tid] += red[tid + st];
        __syncthreads();
    }
    if (tid == 0) out[0] = red[0] / (float)N2;
}

// ---------------------------------------------------------------------------
extern "C" void kernel_launch(void* const* d_in, const int* in_sizes, int n_in,
                              void* d_out, int out_size, void* d_ws, size_t ws_size,
                              hipStream_t stream) {
    (void)in_sizes; (void)n_in; (void)out_size; (void)ws_size;
    const float* x = (const float*)d_in[0];
    float* out = (float*)d_out;

    char* ws = (char*)d_ws;
    bf16_t* xn     = (bf16_t*)ws;                          // 4 MB
    float*  rowsum = (float*)(ws + (size_t)N2 * DIM * 2);  // 16 KB
    float*  pos    = rowsum + N2;
    float*  diag   = pos + N2;
    int*    counter = (int*)(diag + N2);

    k_prep<<<512, 256, 0, stream>>>(x, xn, pos, diag, rowsum, counter);
    k_simgemm<<<528, 256, 0, stream>>>(xn, rowsum, pos, diag, counter, out);
}

// Round 3
// 84.251 us; speedup vs baseline: 1.3421x; 1.3421x over previous
//
#include <hip/hip_runtime.h>
#include <hip/hip_bf16.h>
#include <math.h>

typedef __bf16 bf16_t;
typedef __bf16 bf16x8 __attribute__((ext_vector_type(8)));
typedef float f32x4 __attribute__((ext_vector_type(4)));

#define N2 4096
#define NHALF 2048
#define DIM 512
#define TEMP_INV 2.0f   // 1/TEMPERATURE

// ---------------------------------------------------------------------------
// Kernel 1 (fused prep): one wave per row-PAIR (i, i+N). Loads both fp32 rows,
// computes norms + cross-dot, writes both bf16 rows, pos[i]=pos[p] (symmetric),
// diag per row from the bf16-rounded values (matches what the GEMM will sum),
// and zeroes this block's slice of rowsum.
// ---------------------------------------------------------------------------
__global__ __launch_bounds__(256) void k_prep(const float* __restrict__ x,
                                              bf16_t* __restrict__ xn,
                                              float* __restrict__ pos,
                                              float* __restrict__ diag,
                                              float* __restrict__ rowsum) {
    const int pair = blockIdx.x * 4 + (threadIdx.x >> 6);   // 0..2047
    const int lane = threadIdx.x & 63;
    const int rowi = pair;
    const int rowp = pair + NHALF;

    const float4* xi = reinterpret_cast<const float4*>(x + (size_t)rowi * DIM);
    const float4* xp = reinterpret_cast<const float4*>(x + (size_t)rowp * DIM);
    float4 a0 = xi[lane * 2], a1 = xi[lane * 2 + 1];
    float4 b0 = xp[lane * 2], b1 = xp[lane * 2 + 1];

    float ssi = a0.x*a0.x + a0.y*a0.y + a0.z*a0.z + a0.w*a0.w
              + a1.x*a1.x + a1.y*a1.y + a1.z*a1.z + a1.w*a1.w;
    float ssp = b0.x*b0.x + b0.y*b0.y + b0.z*b0.z + b0.w*b0.w
              + b1.x*b1.x + b1.y*b1.y + b1.z*b1.z + b1.w*b1.w;
    float dot = a0.x*b0.x + a0.y*b0.y + a0.z*b0.z + a0.w*b0.w
              + a1.x*b1.x + a1.y*b1.y + a1.z*b1.z + a1.w*b1.w;
#pragma unroll
    for (int off = 32; off; off >>= 1) {
        ssi += __shfl_xor(ssi, off, 64);
        ssp += __shfl_xor(ssp, off, 64);
        dot += __shfl_xor(dot, off, 64);
    }
    const float ni = fmaxf(sqrtf(ssi), 1e-8f);
    const float np = fmaxf(sqrtf(ssp), 1e-8f);
    const float sci = 1.0f / ni, scp = 1.0f / np;

    float va[8] = {a0.x, a0.y, a0.z, a0.w, a1.x, a1.y, a1.z, a1.w};
    float vb[8] = {b0.x, b0.y, b0.z, b0.w, b1.x, b1.y, b1.z, b1.w};
    bf16x8 oi, op;
    float dii = 0.0f, dpp = 0.0f;
#pragma unroll
    for (int t = 0; t < 8; ++t) {
        oi[t] = (bf16_t)(va[t] * sci);
        op[t] = (bf16_t)(vb[t] * scp);
        float fi = (float)oi[t], fp_ = (float)op[t];
        dii += fi * fi;
        dpp += fp_ * fp_;
    }
    *reinterpret_cast<bf16x8*>(xn + (size_t)rowi * DIM + lane * 8) = oi;
    *reinterpret_cast<bf16x8*>(xn + (size_t)rowp * DIM + lane * 8) = op;
#pragma unroll
    for (int off = 32; off; off >>= 1) {
        dii += __shfl_xor(dii, off, 64);
        dpp += __shfl_xor(dpp, off, 64);
    }
    if (lane == 0) {
        const float pv = TEMP_INV * dot * sci * scp;
        pos[rowi] = pv;
        pos[rowp] = pv;          // sim is symmetric: pos[i] == pos[i+N]
        diag[rowi] = TEMP_INV * dii;
        diag[rowp] = TEMP_INV * dpp;
    }
    // zero rowsum (8 entries per block covers 4096 over 512 blocks)
    if (threadIdx.x < 8) rowsum[blockIdx.x * 8 + threadIdx.x] = 0.0f;
}

// ---------------------------------------------------------------------------
// Kernel 2: symmetric sim-GEMM, upper-triangle blocks only (528 of 1024).
// 128x128 tile, 4 waves 2x2, BK=32, mfma 16x16x32 bf16.
// TRUE 2-phase pipeline (T3 minimum template, m248v2-verified pattern):
//   STAGE(next tile) -> s_waitcnt vmcnt(4) -> s_barrier -> ds_read ->
//   (compiler lgkmcnt) -> 16x MFMA -> s_barrier
// Counted vmcnt: each thread has exactly 4 staging loads per tile, so
// vmcnt(4) confirms the PREVIOUS tile landed while the just-issued 4 stay in
// flight across the whole compute phase — never a full drain in the loop.
// K-loop fully unrolled so the buffer index is compile-time (avoids the
// compiler's conservative vmcnt(0) from LDS alias uncertainty).
// LDS 33KB -> 4 blocks/CU by LDS; grid 528 = 2.06/CU all co-resident.
// ---------------------------------------------------------------------------
__device__ __forceinline__ void load_lds16(const bf16_t* g, bf16_t* l) {
    __builtin_amdgcn_global_load_lds(
        (const __attribute__((address_space(1))) unsigned int*)g,
        (__attribute__((address_space(3))) unsigned int*)l,
        16, 0, 0);
}

__global__ __launch_bounds__(256) void k_simgemm(const bf16_t* __restrict__ xn,
                                                 float* __restrict__ rowsum) {
    __shared__ bf16_t As[2][128 * 32];   // 2 x 8KB
    __shared__ bf16_t Bs[2][128 * 32];   // 2 x 8KB
    __shared__ float  rpA[128];
    __shared__ float  rpB[128];

    // unrank blockIdx.x -> (bm <= bn) upper-triangle pair
    const int t = blockIdx.x;
    int bn = (int)((sqrtf(8.0f * (float)t + 1.0f) - 1.0f) * 0.5f);
    while ((bn * (bn + 1)) / 2 > t) --bn;
    while (((bn + 1) * (bn + 2)) / 2 <= t) ++bn;
    const int bm = t - (bn * (bn + 1)) / 2;
    const bool diagb = (bm == bn);

    const int tid  = threadIdx.x;
    const int lane = tid & 63;
    const int wid  = tid >> 6;
    const int wr   = wid >> 1;
    const int wc   = wid & 1;
    const int q    = lane >> 4;
    const int l15  = lane & 15;

    if (tid < 128) { rpA[tid] = 0.0f; rpB[tid] = 0.0f; }

    // Staging: one K-tile = 128 rows x 32 cols bf16 = 8KB = 256 thr x 2x16B.
    // thread t covers rows (t>>2) and 64+(t>>2), col (t&3)*8.
    // LDS linear: row*32 + col == t*8 (+2048 for second half): wave-uniform
    // base + lane*16B as global_load_lds requires.
    const bf16_t* gA = xn + (size_t)(bm * 128 + (tid >> 2)) * DIM + (tid & 3) * 8;
    const bf16_t* gB = xn + (size_t)(bn * 128 + (tid >> 2)) * DIM + (tid & 3) * 8;

    f32x4 acc[4][4] = {};

    // prologue: stage K-tile 0 into buffer 0
    load_lds16(gA,                    &As[0][tid * 8]);
    load_lds16(gA + (size_t)64 * DIM, &As[0][2048 + tid * 8]);
    load_lds16(gB,                    &Bs[0][tid * 8]);
    load_lds16(gB + (size_t)64 * DIM, &Bs[0][2048 + tid * 8]);

#pragma unroll
    for (int kt = 0; kt < 16; ++kt) {
        const int cur = kt & 1;            // compile-time after full unroll
        // phase A: issue next K-tile into the other buffer (its previous
        // reads retired: the kt-1 MFMAs' lgkmcnt + end barrier guarantee it)
        if (kt < 15) {
            const bf16_t* gA1 = gA + (size_t)(kt + 1) * 32;
            const bf16_t* gB1 = gB + (size_t)(kt + 1) * 32;
            load_lds16(gA1,                    &As[cur ^ 1][tid * 8]);
            load_lds16(gA1 + (size_t)64 * DIM, &As[cur ^ 1][2048 + tid * 8]);
            load_lds16(gB1,                    &Bs[cur ^ 1][tid * 8]);
            load_lds16(gB1 + (size_t)64 * DIM, &Bs[cur ^ 1][2048 + tid * 8]);
            asm volatile("s_waitcnt vmcnt(4)" ::: "memory");
        } else {
            asm volatile("s_waitcnt vmcnt(0)" ::: "memory");
        }
        __builtin_amdgcn_s_barrier();      // current tile resident for all waves

        // phase B: compute current tile
        bf16x8 af[4], bv[4];
#pragma unroll
        for (int mt = 0; mt < 4; ++mt)
            af[mt] = *reinterpret_cast<const bf16x8*>(
                &As[cur][(wr * 64 + mt * 16 + l15) * 32 + q * 8]);
#pragma unroll
        for (int nt = 0; nt < 4; ++nt)
            bv[nt] = *reinterpret_cast<const bf16x8*>(
                &Bs[cur][(wc * 64 + nt * 16 + l15) * 32 + q * 8]);
#pragma unroll
        for (int mt = 0; mt < 4; ++mt)
#pragma unroll
            for (int nt = 0; nt < 4; ++nt)
                acc[mt][nt] = __builtin_amdgcn_mfma_f32_16x16x32_bf16(
                    af[mt], bv[nt], acc[mt][nt], 0, 0, 0);
        // end barrier: by MFMA issue, each wave's ds_reads retired (compiler
        // lgkmcnt) -> after this barrier buf[cur] is safe to overwrite
        __builtin_amdgcn_s_barrier();
    }

    // Epilogue. C/D: row = wr*64+mt*16+q*4+r, col = wc*64+nt*16+l15.
    float colacc[4] = {0.0f, 0.0f, 0.0f, 0.0f};
#pragma unroll
    for (int mt = 0; mt < 4; ++mt) {
        float rowp[4] = {0.0f, 0.0f, 0.0f, 0.0f};
#pragma unroll
        for (int nt = 0; nt < 4; ++nt)
#pragma unroll
            for (int r = 0; r < 4; ++r) {
                float e = __expf(TEMP_INV * acc[mt][nt][r]);
                rowp[r] += e;
                colacc[nt] += e;
            }
#pragma unroll
        for (int r = 0; r < 4; ++r) {
            float p = rowp[r];
            p += __shfl_xor(p, 1, 64);
            p += __shfl_xor(p, 2, 64);
            p += __shfl_xor(p, 4, 64);
            p += __shfl_xor(p, 8, 64);
            if (l15 == 0) atomicAdd(&rpA[wr * 64 + mt * 16 + q * 4 + r], p);
        }
    }
    if (!diagb) {
#pragma unroll
        for (int nt = 0; nt < 4; ++nt) {
            float c = colacc[nt];
            c += __shfl_xor(c, 16, 64);
            c += __shfl_xor(c, 32, 64);
            if (q == 0) atomicAdd(&rpB[wc * 64 + nt * 16 + l15], c);
        }
    }
    __syncthreads();
    if (tid < 128) {
        atomicAdd(&rowsum[bm * 128 + tid], rpA[tid]);
    } else if (!diagb) {
        atomicAdd(&rowsum[bn * 128 + (tid - 128)], rpB[tid - 128]);
    }
}

// ---------------------------------------------------------------------------
// Kernel 3: loss = mean_i( log(S_i - exp(diag_i)) - pos_i )
// float4-vectorized single block (4 unrolled rounds of 3x16B loads).
// ---------------------------------------------------------------------------
__global__ __launch_bounds__(256) void k_finalize(const float* __restrict__ rowsum,
                                                  const float* __restrict__ pos,
                                                  const float* __restrict__ diag,
                                                  float* __restrict__ out) {
    __shared__ float red[256];
    const float4* rs4 = reinterpret_cast<const float4*>(rowsum);
    const float4* ps4 = reinterpret_cast<const float4*>(pos);
    const float4* dg4 = reinterpret_cast<const float4*>(diag);
    float s = 0.0f;
#pragma unroll
    for (int it = 0; it < 4; ++it) {
        const int i = it * 256 + threadIdx.x;   // 1024 float4 = 4096 floats
        float4 r = rs4[i];
        float4 p = ps4[i];
        float4 d = dg4[i];
        s += __logf(r.x - __expf(d.x)) - p.x;
        s += __logf(r.y - __expf(d.y)) - p.y;
        s += __logf(r.z - __expf(d.z)) - p.z;
        s += __logf(r.w - __expf(d.w)) - p.w;
    }
    red[threadIdx.x] = s;
    __syncthreads();
    for (int st = 128; st; st >>= 1) {
        if (threadIdx.x < st) red[threadIdx.x] += red[threadIdx.x + st];
        __syncthreads();
    }
    if (threadIdx.x == 0) out[0] = red[0] / (float)N2;
}

// ---------------------------------------------------------------------------
extern "C" void kernel_launch(void* const* d_in, const int* in_sizes, int n_in,
                              void* d_out, int out_size, void* d_ws, size_t ws_size,
                              hipStream_t stream) {
    (void)in_sizes; (void)n_in; (void)out_size; (void)ws_size;
    const float* x = (const float*)d_in[0];
    float* out = (float*)d_out;

    char* ws = (char*)d_ws;
    bf16_t* xn     = (bf16_t*)ws;                          // 4 MB
    float*  rowsum = (float*)(ws + (size_t)N2 * DIM * 2);  // 16 KB
    float*  pos    = rowsum + N2;
    float*  diag   = pos + N2;

    k_prep<<<512, 256, 0, stream>>>(x, xn, pos, diag, rowsum);
    k_simgemm<<<528, 256, 0, stream>>>(xn, rowsum);
    k_finalize<<<1, 256, 0, stream>>>(rowsum, pos, diag, out);
}

// Round 4
// 78.308 us; speedup vs baseline: 1.4440x; 1.0759x over previous
//
#include <hip/hip_runtime.h>
#include <hip/hip_bf16.h>
#include <math.h>

typedef __bf16 bf16_t;
typedef __bf16 bf16x8 __attribute__((ext_vector_type(8)));
typedef float f32x4 __attribute__((ext_vector_type(4)));

#define N2 4096
#define NHALF 2048
#define DIM 512
#define TEMP_INV 2.0f   // 1/TEMPERATURE

// ---------------------------------------------------------------------------
// Kernel 1 (fused prep): one wave per row-PAIR (i, i+N). Loads both fp32 rows,
// computes norms + cross-dot, writes both bf16 rows, pos[i]=pos[p] (symmetric),
// diag per row from the bf16-rounded values (matches what the GEMM will sum),
// and zeroes this block's slice of rowsum.
// ---------------------------------------------------------------------------
__global__ __launch_bounds__(256) void k_prep(const float* __restrict__ x,
                                              bf16_t* __restrict__ xn,
                                              float* __restrict__ pos,
                                              float* __restrict__ diag,
                                              float* __restrict__ rowsum) {
    const int pair = blockIdx.x * 4 + (threadIdx.x >> 6);   // 0..2047
    const int lane = threadIdx.x & 63;
    const int rowi = pair;
    const int rowp = pair + NHALF;

    const float4* xi = reinterpret_cast<const float4*>(x + (size_t)rowi * DIM);
    const float4* xp = reinterpret_cast<const float4*>(x + (size_t)rowp * DIM);
    float4 a0 = xi[lane * 2], a1 = xi[lane * 2 + 1];
    float4 b0 = xp[lane * 2], b1 = xp[lane * 2 + 1];

    float ssi = a0.x*a0.x + a0.y*a0.y + a0.z*a0.z + a0.w*a0.w
              + a1.x*a1.x + a1.y*a1.y + a1.z*a1.z + a1.w*a1.w;
    float ssp = b0.x*b0.x + b0.y*b0.y + b0.z*b0.z + b0.w*b0.w
              + b1.x*b1.x + b1.y*b1.y + b1.z*b1.z + b1.w*b1.w;
    float dot = a0.x*b0.x + a0.y*b0.y + a0.z*b0.z + a0.w*b0.w
              + a1.x*b1.x + a1.y*b1.y + a1.z*b1.z + a1.w*b1.w;
#pragma unroll
    for (int off = 32; off; off >>= 1) {
        ssi += __shfl_xor(ssi, off, 64);
        ssp += __shfl_xor(ssp, off, 64);
        dot += __shfl_xor(dot, off, 64);
    }
    const float ni = fmaxf(sqrtf(ssi), 1e-8f);
    const float np = fmaxf(sqrtf(ssp), 1e-8f);
    const float sci = 1.0f / ni, scp = 1.0f / np;

    float va[8] = {a0.x, a0.y, a0.z, a0.w, a1.x, a1.y, a1.z, a1.w};
    float vb[8] = {b0.x, b0.y, b0.z, b0.w, b1.x, b1.y, b1.z, b1.w};
    bf16x8 oi, op;
    float dii = 0.0f, dpp = 0.0f;
#pragma unroll
    for (int t = 0; t < 8; ++t) {
        oi[t] = (bf16_t)(va[t] * sci);
        op[t] = (bf16_t)(vb[t] * scp);
        float fi = (float)oi[t], fp_ = (float)op[t];
        dii += fi * fi;
        dpp += fp_ * fp_;
    }
    *reinterpret_cast<bf16x8*>(xn + (size_t)rowi * DIM + lane * 8) = oi;
    *reinterpret_cast<bf16x8*>(xn + (size_t)rowp * DIM + lane * 8) = op;
#pragma unroll
    for (int off = 32; off; off >>= 1) {
        dii += __shfl_xor(dii, off, 64);
        dpp += __shfl_xor(dpp, off, 64);
    }
    if (lane == 0) {
        const float pv = TEMP_INV * dot * sci * scp;
        pos[rowi] = pv;
        pos[rowp] = pv;          // sim is symmetric: pos[i] == pos[i+N]
        diag[rowi] = TEMP_INV * dii;
        diag[rowp] = TEMP_INV * dpp;
    }
    // zero rowsum (8 entries per block covers 4096 over 512 blocks)
    if (threadIdx.x < 8) rowsum[blockIdx.x * 8 + threadIdx.x] = 0.0f;
}

// ---------------------------------------------------------------------------
// Kernel 2: symmetric sim-GEMM, upper-triangle blocks only (528 of 1024).
// 128x128 tile, 4 waves 2x2, BK=32, mfma 16x16x32 bf16.
//
// T2 XOR-swizzle (both-sides-or-neither, rule #21): the un-swizzled [128][32]
// tile (64B rows) makes every ds_read_b128 an 8-WAY bank conflict
// (bank = row*16+q*4 mod 32 hits only 2 groups over 16 rows). Fix:
//   - global SOURCE slot permuted per thread: slot_g = (t&3) ^ ((t>>3)&3)
//     (global_load_lds dest must stay linear),
//   - fragment READ slot permuted identically: slot_r = q ^ ((l15>>1)&3).
// Post-swizzle: 2 lanes/bank = free (m136). Pure lane permutation ->
// arithmetic bit-identical.
//
// Triple-buffered 1-barrier pipeline: per K-step
//   vmcnt(4) -> s_barrier -> stage(kt+2) -> ds_read(kt) -> 16x MFMA
// One barrier/step (all waves passing barrier(kt) implies their kt-1
// ds_reads retired via the MFMAs' lgkmcnt, so overwriting buf[(kt-1)%3]
// is safe); tile kt+2 has 2 full steps of latency cover; vmcnt(4) leaves
// tile kt+1's 4 loads in flight (never drains to 0 in the loop).
// LDS 49KB -> 3 blocks/CU; grid 528 = 2.06/CU fully co-resident.
// ---------------------------------------------------------------------------
__device__ __forceinline__ void load_lds16(const bf16_t* g, bf16_t* l) {
    __builtin_amdgcn_global_load_lds(
        (const __attribute__((address_space(1))) unsigned int*)g,
        (__attribute__((address_space(3))) unsigned int*)l,
        16, 0, 0);
}

__global__ __launch_bounds__(256) void k_simgemm(const bf16_t* __restrict__ xn,
                                                 float* __restrict__ rowsum) {
    __shared__ bf16_t As[3][128 * 32];   // 3 x 8KB
    __shared__ bf16_t Bs[3][128 * 32];   // 3 x 8KB
    __shared__ float  rpA[128];
    __shared__ float  rpB[128];

    // unrank blockIdx.x -> (bm <= bn) upper-triangle pair
    const int t = blockIdx.x;
    int bn = (int)((sqrtf(8.0f * (float)t + 1.0f) - 1.0f) * 0.5f);
    while ((bn * (bn + 1)) / 2 > t) --bn;
    while (((bn + 1) * (bn + 2)) / 2 <= t) ++bn;
    const int bm = t - (bn * (bn + 1)) / 2;
    const bool diagb = (bm == bn);

    const int tid  = threadIdx.x;
    const int lane = tid & 63;
    const int wid  = tid >> 6;
    const int wr   = wid >> 1;
    const int wc   = wid & 1;
    const int q    = lane >> 4;
    const int l15  = lane & 15;

    if (tid < 128) { rpA[tid] = 0.0f; rpB[tid] = 0.0f; }

    // Staging: one K-tile = 128 rows x 32 cols bf16 = 8KB.
    // thread t covers rows (t>>2) and 64+(t>>2); its GLOBAL slot within the
    // row's 64B is XOR-swizzled: ((t&3) ^ ((t>>3)&3)). LDS dest stays linear
    // (t*8 / 2048+t*8) as global_load_lds requires. Note (row>>1)&3 is the
    // same for row t>>2 and row 64+(t>>2), and invariant across K-tiles.
    const int slot_g = (tid & 3) ^ ((tid >> 3) & 3);
    const bf16_t* gA = xn + (size_t)(bm * 128 + (tid >> 2)) * DIM + slot_g * 8;
    const bf16_t* gB = xn + (size_t)(bn * 128 + (tid >> 2)) * DIM + slot_g * 8;

    // fragment-read swizzle: same involution, slot_r = q ^ ((row>>1)&3),
    // and (row>>1)&3 == (l15>>1)&3 for row = {wr,wc}*64 + {mt,nt}*16 + l15.
    const int rsw = (q ^ ((l15 >> 1) & 3)) * 8;
    const int arow = (wr * 64 + l15) * 32 + rsw;   // + mt*16*32
    const int brow = (wc * 64 + l15) * 32 + rsw;   // + nt*16*32

    f32x4 acc[4][4] = {};

    // prologue: stage K-tiles 0 and 1
    load_lds16(gA,                         &As[0][tid * 8]);
    load_lds16(gA + (size_t)64 * DIM,      &As[0][2048 + tid * 8]);
    load_lds16(gB,                         &Bs[0][tid * 8]);
    load_lds16(gB + (size_t)64 * DIM,      &Bs[0][2048 + tid * 8]);
    load_lds16(gA + 32,                    &As[1][tid * 8]);
    load_lds16(gA + (size_t)64 * DIM + 32, &As[1][2048 + tid * 8]);
    load_lds16(gB + 32,                    &Bs[1][tid * 8]);
    load_lds16(gB + (size_t)64 * DIM + 32, &Bs[1][2048 + tid * 8]);

#pragma unroll
    for (int kt = 0; kt < 16; ++kt) {
        // confirm tile kt resident (own loads), leave tile kt+1's in flight
        if (kt < 15) asm volatile("s_waitcnt vmcnt(4)" ::: "memory");
        else         asm volatile("s_waitcnt vmcnt(0)" ::: "memory");
        __builtin_amdgcn_s_barrier();      // whole tile kt resident; all
                                           // waves' kt-1 reads retired
        __builtin_amdgcn_sched_barrier(0); // pin: nothing floats above

        if (kt + 2 < 16) {                 // stage tile kt+2 (2-step cover)
            const int nb = (kt + 2) % 3;   // == (kt-1)%3, safe per barrier
            const bf16_t* gA2 = gA + (kt + 2) * 32;
            const bf16_t* gB2 = gB + (kt + 2) * 32;
            load_lds16(gA2,                    &As[nb][tid * 8]);
            load_lds16(gA2 + (size_t)64 * DIM, &As[nb][2048 + tid * 8]);
            load_lds16(gB2,                    &Bs[nb][tid * 8]);
            load_lds16(gB2 + (size_t)64 * DIM, &Bs[nb][2048 + tid * 8]);
        }

        const int cb = kt % 3;             // compile-time after unroll
        bf16x8 af[4], bv[4];
#pragma unroll
        for (int mt = 0; mt < 4; ++mt)
            af[mt] = *reinterpret_cast<const bf16x8*>(&As[cb][arow + mt * 512]);
#pragma unroll
        for (int nt = 0; nt < 4; ++nt)
            bv[nt] = *reinterpret_cast<const bf16x8*>(&Bs[cb][brow + nt * 512]);
#pragma unroll
        for (int mt = 0; mt < 4; ++mt)
#pragma unroll
            for (int nt = 0; nt < 4; ++nt)
                acc[mt][nt] = __builtin_amdgcn_mfma_f32_16x16x32_bf16(
                    af[mt], bv[nt], acc[mt][nt], 0, 0, 0);
    }

    // Epilogue. C/D: row = wr*64+mt*16+q*4+r, col = wc*64+nt*16+l15.
    float colacc[4] = {0.0f, 0.0f, 0.0f, 0.0f};
#pragma unroll
    for (int mt = 0; mt < 4; ++mt) {
        float rowp[4] = {0.0f, 0.0f, 0.0f, 0.0f};
#pragma unroll
        for (int nt = 0; nt < 4; ++nt)
#pragma unroll
            for (int r = 0; r < 4; ++r) {
                float e = __expf(TEMP_INV * acc[mt][nt][r]);
                rowp[r] += e;
                colacc[nt] += e;
            }
#pragma unroll
        for (int r = 0; r < 4; ++r) {
            float p = rowp[r];
            p += __shfl_xor(p, 1, 64);
            p += __shfl_xor(p, 2, 64);
            p += __shfl_xor(p, 4, 64);
            p += __shfl_xor(p, 8, 64);
            if (l15 == 0) atomicAdd(&rpA[wr * 64 + mt * 16 + q * 4 + r], p);
        }
    }
    if (!diagb) {
#pragma unroll
        for (int nt = 0; nt < 4; ++nt) {
            float c = colacc[nt];
            c += __shfl_xor(c, 16, 64);
            c += __shfl_xor(c, 32, 64);
            if (q == 0) atomicAdd(&rpB[wc * 64 + nt * 16 + l15], c);
        }
    }
    __syncthreads();
    if (tid < 128) {
        atomicAdd(&rowsum[bm * 128 + tid], rpA[tid]);
    } else if (!diagb) {
        atomicAdd(&rowsum[bn * 128 + (tid - 128)], rpB[tid - 128]);
    }
}

// ---------------------------------------------------------------------------
// Kernel 3: loss = mean_i( log(S_i - exp(diag_i)) - pos_i )
// float4-vectorized single block (4 unrolled rounds of 3x16B loads).
// ---------------------------------------------------------------------------
__global__ __launch_bounds__(256) void k_finalize(const float* __restrict__ rowsum,
                                                  const float* __restrict__ pos,
                                                  const float* __restrict__ diag,
                                                  float* __restrict__ out) {
    __shared__ float red[256];
    const float4* rs4 = reinterpret_cast<const float4*>(rowsum);
    const float4* ps4 = reinterpret_cast<const float4*>(pos);
    const float4* dg4 = reinterpret_cast<const float4*>(diag);
    float s = 0.0f;
#pragma unroll
    for (int it = 0; it < 4; ++it) {
        const int i = it * 256 + threadIdx.x;   // 1024 float4 = 4096 floats
        float4 r = rs4[i];
        float4 p = ps4[i];
        float4 d = dg4[i];
        s += __logf(r.x - __expf(d.x)) - p.x;
        s += __logf(r.y - __expf(d.y)) - p.y;
        s += __logf(r.z - __expf(d.z)) - p.z;
        s += __logf(r.w - __expf(d.w)) - p.w;
    }
    red[threadIdx.x] = s;
    __syncthreads();
    for (int st = 128; st; st >>= 1) {
        if (threadIdx.x < st) red[threadIdx.x] += red[threadIdx.x + st];
        __syncthreads();
    }
    if (threadIdx.x == 0) out[0] = red[0] / (float)N2;
}

// ---------------------------------------------------------------------------
extern "C" void kernel_launch(void* const* d_in, const int* in_sizes, int n_in,
                              void* d_out, int out_size, void* d_ws, size_t ws_size,
                              hipStream_t stream) {
    (void)in_sizes; (void)n_in; (void)out_size; (void)ws_size;
    const float* x = (const float*)d_in[0];
    float* out = (float*)d_out;

    char* ws = (char*)d_ws;
    bf16_t* xn     = (bf16_t*)ws;                          // 4 MB
    float*  rowsum = (float*)(ws + (size_t)N2 * DIM * 2);  // 16 KB
    float*  pos    = rowsum + N2;
    float*  diag   = pos + N2;

    k_prep<<<512, 256, 0, stream>>>(x, xn, pos, diag, rowsum);
    k_simgemm<<<528, 256, 0, stream>>>(xn, rowsum);
    k_finalize<<<1, 256, 0, stream>>>(rowsum, pos, diag, out);
}